// Round 1
// baseline (353.045 us; speedup 1.0000x reference)
//
#include <hip/hip_runtime.h>
#include <math.h>

#define NCLS 19
#define DIM  128
#define CD   (NCLS * DIM)   // 2432 floats

// Pass 1: per-class sums + counts.
// Block = 1024 threads (16 waves). Each 32-lane half-wave handles one row per
// iteration via float4 loads (lane l32 loads dims [4*l32, 4*l32+3]).
// Accumulate into LDS with atomics, flush once per block with global atomics.
__global__ __launch_bounds__(1024) void k_accum(const float4* __restrict__ in4,
                                                const int* __restrict__ tgt,
                                                float* __restrict__ gsums,
                                                float* __restrict__ gcounts,
                                                int n) {
    __shared__ float ls[CD];
    __shared__ float lc[NCLS];
    const int tid = threadIdx.x;
    for (int i = tid; i < CD; i += 1024) ls[i] = 0.0f;
    if (tid < NCLS) lc[tid] = 0.0f;
    __syncthreads();

    const int l32 = tid & 31;
    const int rib = tid >> 5;              // row-in-block-step: 0..31
    const int stride = gridDim.x * 32;     // rows consumed per grid step

    for (int row = blockIdx.x * 32 + rib; row < n; row += stride) {
        float4 v = in4[(size_t)row * 32 + l32];
        int c = tgt[row];
        int base = c * DIM + l32 * 4;
        atomicAdd(&ls[base + 0], v.x);
        atomicAdd(&ls[base + 1], v.y);
        atomicAdd(&ls[base + 2], v.z);
        atomicAdd(&ls[base + 3], v.w);
        if (l32 == 0) atomicAdd(&lc[c], 1.0f);
    }
    __syncthreads();

    for (int i = tid; i < CD; i += 1024) atomicAdd(&gsums[i], ls[i]);
    if (tid < NCLS) atomicAdd(&gcounts[tid], lc[tid]);
}

// Pass 2: distances. Each block stages centers (= sums/counts) into LDS, then
// streams rows with the same coalesced float4 pattern. 32-lane shuffle reduce
// per row -> sqrt -> per-thread accumulator -> block reduce -> one atomicAdd.
__global__ __launch_bounds__(256) void k_dist(const float4* __restrict__ in4,
                                              const int* __restrict__ tgt,
                                              const float* __restrict__ gsums,
                                              const float* __restrict__ gcounts,
                                              float* __restrict__ out,
                                              int n, float inv_n) {
    __shared__ __align__(16) float lcent[CD];
    __shared__ float red[256];
    const int tid = threadIdx.x;

    for (int i = tid; i < CD; i += 256) lcent[i] = gsums[i] / gcounts[i >> 7];
    __syncthreads();

    const int l32 = tid & 31;
    const int rib = tid >> 5;              // 0..7
    const int stride = gridDim.x * 8;
    float acc = 0.0f;

    for (int row = blockIdx.x * 8 + rib; row < n; row += stride) {
        float4 v = in4[(size_t)row * 32 + l32];
        int c = tgt[row];
        float4 ce = *(const float4*)&lcent[c * DIM + l32 * 4];
        float dx = v.x - ce.x, dy = v.y - ce.y, dz = v.z - ce.z, dw = v.w - ce.w;
        float d2 = dx * dx + dy * dy + dz * dz + dw * dw;
        // reduce across the 32-lane row group
        for (int off = 16; off > 0; off >>= 1)
            d2 += __shfl_down(d2, off, 32);
        if (l32 == 0) acc += sqrtf(d2);
    }

    red[tid] = acc;
    __syncthreads();
    for (int s = 128; s > 0; s >>= 1) {
        if (tid < s) red[tid] += red[tid + s];
        __syncthreads();
    }
    if (tid == 0) atomicAdd(out, red[0] * inv_n);
}

extern "C" void kernel_launch(void* const* d_in, const int* in_sizes, int n_in,
                              void* d_out, int out_size, void* d_ws, size_t ws_size,
                              hipStream_t stream) {
    const float* in  = (const float*)d_in[0];
    const int*   tgt = (const int*)d_in[1];
    const int n = in_sizes[0] / DIM;

    float* gsums   = (float*)d_ws;         // [19][128]
    float* gcounts = gsums + CD;           // [19]
    float* out     = (float*)d_out;

    // Harness re-poisons d_out/d_ws to 0xAA before every timed call.
    hipMemsetAsync(d_ws, 0, (CD + NCLS) * sizeof(float), stream);
    hipMemsetAsync(d_out, 0, sizeof(float), stream);

    k_accum<<<256, 1024, 0, stream>>>((const float4*)in, tgt, gsums, gcounts, n);
    k_dist<<<1024, 256, 0, stream>>>((const float4*)in, tgt, gsums, gcounts, out,
                                     n, 1.0f / (float)n);
}

// Round 2
// 352.200 us; speedup vs baseline: 1.0024x; 1.0024x over previous
//
#include <hip/hip_runtime.h>
#include <math.h>

#define NCLS 19
#define DIM  128
#define CD   (NCLS * DIM)   // 2432 floats

// Pass 1: per-class sums + counts.
// Block = 1024 threads (16 waves). Each 32-lane group handles one row per
// iteration via float4 loads (lane l32 loads dims [4*l32, 4*l32+3]).
// Accumulate into LDS with NATIVE float atomics (ds_add_f32 via
// unsafeAtomicAdd — default atomicAdd(float*) is a CAS loop on gfx950 and
// serialized catastrophically in R1: VALUBusy 0.85%). Flush once per block
// with native global_atomic_add_f32.
__global__ __launch_bounds__(1024) void k_accum(const float4* __restrict__ in4,
                                                const int* __restrict__ tgt,
                                                float* __restrict__ gsums,
                                                int* __restrict__ gcounts,
                                                int n) {
    __shared__ float ls[CD];
    __shared__ int lc[NCLS];
    const int tid = threadIdx.x;
    for (int i = tid; i < CD; i += 1024) ls[i] = 0.0f;
    if (tid < NCLS) lc[tid] = 0;
    __syncthreads();

    const int l32 = tid & 31;
    const int rib = tid >> 5;              // row-group in block: 0..31
    const int stride = gridDim.x * 32;     // rows consumed per grid step

    for (int row = blockIdx.x * 32 + rib; row < n; row += stride) {
        float4 v = in4[(size_t)row * 32 + l32];
        int c = tgt[row];
        int base = c * DIM + l32 * 4;
        unsafeAtomicAdd(&ls[base + 0], v.x);
        unsafeAtomicAdd(&ls[base + 1], v.y);
        unsafeAtomicAdd(&ls[base + 2], v.z);
        unsafeAtomicAdd(&ls[base + 3], v.w);
        if (l32 == 0) atomicAdd(&lc[c], 1);   // int atomics are always native
    }
    __syncthreads();

    for (int i = tid; i < CD; i += 1024) unsafeAtomicAdd(&gsums[i], ls[i]);
    if (tid < NCLS) atomicAdd(&gcounts[tid], lc[tid]);
}

// Pass 2: distances. Each block stages centers (= sums/counts) into LDS, then
// streams rows with the same coalesced float4 pattern. 32-lane shuffle reduce
// per row -> sqrt -> per-thread accumulator -> block reduce -> ONE native
// global fadd per block (R1's default atomicAdd was a 1024-way-contended CAS
// loop on a single address — ~200 µs of pure serialization).
__global__ __launch_bounds__(256) void k_dist(const float4* __restrict__ in4,
                                              const int* __restrict__ tgt,
                                              const float* __restrict__ gsums,
                                              const int* __restrict__ gcounts,
                                              float* __restrict__ out,
                                              int n, float inv_n) {
    __shared__ __align__(16) float lcent[CD];
    __shared__ float red[256];
    const int tid = threadIdx.x;

    for (int i = tid; i < CD; i += 256)
        lcent[i] = gsums[i] / (float)gcounts[i >> 7];
    __syncthreads();

    const int l32 = tid & 31;
    const int rib = tid >> 5;              // 0..7
    const int stride = gridDim.x * 8;
    float acc = 0.0f;

    for (int row = blockIdx.x * 8 + rib; row < n; row += stride) {
        float4 v = in4[(size_t)row * 32 + l32];
        int c = tgt[row];
        float4 ce = *(const float4*)&lcent[c * DIM + l32 * 4];
        float dx = v.x - ce.x, dy = v.y - ce.y, dz = v.z - ce.z, dw = v.w - ce.w;
        float d2 = dx * dx + dy * dy + dz * dz + dw * dw;
        // reduce across the 32-lane row group
        for (int off = 16; off > 0; off >>= 1)
            d2 += __shfl_down(d2, off, 32);
        if (l32 == 0) acc += sqrtf(d2);
    }

    red[tid] = acc;
    __syncthreads();
    for (int s = 128; s > 0; s >>= 1) {
        if (tid < s) red[tid] += red[tid + s];
        __syncthreads();
    }
    if (tid == 0) unsafeAtomicAdd(out, red[0] * inv_n);
}

extern "C" void kernel_launch(void* const* d_in, const int* in_sizes, int n_in,
                              void* d_out, int out_size, void* d_ws, size_t ws_size,
                              hipStream_t stream) {
    const float* in  = (const float*)d_in[0];
    const int*   tgt = (const int*)d_in[1];
    const int n = in_sizes[0] / DIM;

    float* gsums   = (float*)d_ws;             // [19][128]
    int*   gcounts = (int*)(gsums + CD);       // [19]
    float* out     = (float*)d_out;

    // Harness re-poisons d_out/d_ws to 0xAA before every timed call.
    hipMemsetAsync(d_ws, 0, CD * sizeof(float) + NCLS * sizeof(int), stream);
    hipMemsetAsync(d_out, 0, sizeof(float), stream);

    k_accum<<<256, 1024, 0, stream>>>((const float4*)in, tgt, gsums, gcounts, n);
    k_dist<<<1024, 256, 0, stream>>>((const float4*)in, tgt, gsums, gcounts, out,
                                     n, 1.0f / (float)n);
}

// Round 3
// 238.511 us; speedup vs baseline: 1.4802x; 1.4767x over previous
//
#include <hip/hip_runtime.h>
#include <math.h>

#define NCLS 19
#define DIM  128
#define CD   (NCLS * DIM)   // 2432 floats
#define WPB  16             // waves per k_accum block (1024 threads)

// Pass 1: per-class sums + counts, NO LDS ATOMICS.
// R2 post-mortem: LDS atomicAdd was already native ds_add_f32; the 176 us was
// LDS atomic RMW serialization (8 lanes/bank x ~10 cyc RMW turnaround, 16
// waves sharing one LDS pipe). Fix: per-WAVE private tables (16 x 9.5 KB =
// 152 KB LDS) + one row per wave (64 lanes x float2) so accumulation is a
// race-free non-atomic ds_read_b64/add/ds_write_b64 on the wave's own table.
__global__ __launch_bounds__(1024) void k_accum(const float2* __restrict__ in2,
                                                const int* __restrict__ tgt,
                                                float* __restrict__ gsums,
                                                int* __restrict__ gcounts,
                                                int n) {
    __shared__ float ls[WPB * CD];      // 155648 B
    __shared__ int   lcnt[WPB * NCLS]; // 1216 B
    const int tid  = threadIdx.x;
    const int w    = tid >> 6;          // wave 0..15
    const int lane = tid & 63;
    float* tbl = &ls[w * CD];
    int*   cnt = &lcnt[w * NCLS];

    for (int i = tid; i < WPB * CD; i += 1024) ls[i] = 0.0f;
    for (int i = tid; i < WPB * NCLS; i += 1024) lcnt[i] = 0;
    __syncthreads();

    const int stride = gridDim.x * WPB;   // rows per grid step (256*16 = 4096)
    for (int row = blockIdx.x * WPB + w; row < n; row += stride) {
        float2 v = in2[(size_t)row * 64 + lane];   // 512B contiguous per wave
        int c = tgt[row];
        float2 cur = *(float2*)&tbl[c * DIM + lane * 2];
        cur.x += v.x;
        cur.y += v.y;
        *(float2*)&tbl[c * DIM + lane * 2] = cur;  // own table: race-free
        if (lane == 0) cnt[c]++;                   // own table: race-free
    }
    __syncthreads();

    // Reduce the 16 wave tables, flush once per block with native global fadd.
    for (int i = tid; i < CD; i += 1024) {
        float s = 0.0f;
        #pragma unroll
        for (int ww = 0; ww < WPB; ww++) s += ls[ww * CD + i];
        unsafeAtomicAdd(&gsums[i], s);
    }
    if (tid < NCLS) {
        int s = 0;
        #pragma unroll
        for (int ww = 0; ww < WPB; ww++) s += lcnt[ww * NCLS + tid];
        atomicAdd(&gcounts[tid], s);
    }
}

// Pass 2: unchanged from R2 (kept identical so this round's profile isolates
// its true cost — it never appeared in the top-5).
__global__ __launch_bounds__(256) void k_dist(const float4* __restrict__ in4,
                                              const int* __restrict__ tgt,
                                              const float* __restrict__ gsums,
                                              const int* __restrict__ gcounts,
                                              float* __restrict__ out,
                                              int n, float inv_n) {
    __shared__ __align__(16) float lcent[CD];
    __shared__ float red[256];
    const int tid = threadIdx.x;

    for (int i = tid; i < CD; i += 256)
        lcent[i] = gsums[i] / (float)gcounts[i >> 7];
    __syncthreads();

    const int l32 = tid & 31;
    const int rib = tid >> 5;              // 0..7
    const int stride = gridDim.x * 8;
    float acc = 0.0f;

    for (int row = blockIdx.x * 8 + rib; row < n; row += stride) {
        float4 v = in4[(size_t)row * 32 + l32];
        int c = tgt[row];
        float4 ce = *(const float4*)&lcent[c * DIM + l32 * 4];
        float dx = v.x - ce.x, dy = v.y - ce.y, dz = v.z - ce.z, dw = v.w - ce.w;
        float d2 = dx * dx + dy * dy + dz * dz + dw * dw;
        for (int off = 16; off > 0; off >>= 1)
            d2 += __shfl_down(d2, off, 32);
        if (l32 == 0) acc += sqrtf(d2);
    }

    red[tid] = acc;
    __syncthreads();
    for (int s = 128; s > 0; s >>= 1) {
        if (tid < s) red[tid] += red[tid + s];
        __syncthreads();
    }
    if (tid == 0) unsafeAtomicAdd(out, red[0] * inv_n);
}

extern "C" void kernel_launch(void* const* d_in, const int* in_sizes, int n_in,
                              void* d_out, int out_size, void* d_ws, size_t ws_size,
                              hipStream_t stream) {
    const float* in  = (const float*)d_in[0];
    const int*   tgt = (const int*)d_in[1];
    const int n = in_sizes[0] / DIM;

    float* gsums   = (float*)d_ws;             // [19][128]
    int*   gcounts = (int*)(gsums + CD);       // [19]
    float* out     = (float*)d_out;

    hipMemsetAsync(d_ws, 0, CD * sizeof(float) + NCLS * sizeof(int), stream);
    hipMemsetAsync(d_out, 0, sizeof(float), stream);

    k_accum<<<256, 1024, 0, stream>>>((const float2*)in, tgt, gsums, gcounts, n);
    k_dist<<<1024, 256, 0, stream>>>((const float4*)in, tgt, gsums, gcounts, out,
                                     n, 1.0f / (float)n);
}

// Round 4
// 231.805 us; speedup vs baseline: 1.5230x; 1.0289x over previous
//
#include <hip/hip_runtime.h>
#include <math.h>

#define NCLS 19
#define DIM  128
#define CD   (NCLS * DIM)   // 2432 floats
#define WPB  16             // waves per k_accum block (1024 threads)

// Pass 1: per-class sums + counts. Per-wave private LDS tables (race-free,
// no atomics in the hot loop — R3 confirmed LDS atomic RMW was the 176 us
// wall). R4: unroll 4 rows/wave/iter so 4 float2 loads (+4 tgt loads) are in
// flight per wave before the LDS RMWs — R3 had only ~8.3 KB/CU outstanding,
// borderline for ~900cyc HBM latency at 10 B/cyc/CU.
__global__ __launch_bounds__(1024) void k_accum(const float2* __restrict__ in2,
                                                const int* __restrict__ tgt,
                                                float* __restrict__ gsums,
                                                int* __restrict__ gcounts,
                                                int n) {
    __shared__ float ls[WPB * CD];      // 155648 B -> 1 block/CU
    __shared__ int   lcnt[WPB * NCLS];
    const int tid  = threadIdx.x;
    const int w    = tid >> 6;          // wave 0..15
    const int lane = tid & 63;
    float* tbl = &ls[w * CD];
    int*   cnt = &lcnt[w * NCLS];

    for (int i = tid; i < WPB * CD; i += 1024) ls[i] = 0.0f;
    for (int i = tid; i < WPB * NCLS; i += 1024) lcnt[i] = 0;
    __syncthreads();

    const int stride = gridDim.x * WPB;   // 4096 rows per grid step
    int row = blockIdx.x * WPB + w;

    for (; row + 3 * stride < n; row += 4 * stride) {
        // 4 independent loads first: 4x(512B + 4B) in flight per wave
        float2 v0 = in2[(size_t)(row             ) * 64 + lane];
        float2 v1 = in2[(size_t)(row +     stride) * 64 + lane];
        float2 v2 = in2[(size_t)(row + 2 * stride) * 64 + lane];
        float2 v3 = in2[(size_t)(row + 3 * stride) * 64 + lane];
        int c0 = tgt[row];
        int c1 = tgt[row + stride];
        int c2 = tgt[row + 2 * stride];
        int c3 = tgt[row + 3 * stride];
        float2* p0 = (float2*)&tbl[c0 * DIM + lane * 2];
        float2* p1 = (float2*)&tbl[c1 * DIM + lane * 2];
        float2* p2 = (float2*)&tbl[c2 * DIM + lane * 2];
        float2* p3 = (float2*)&tbl[c3 * DIM + lane * 2];
        float2 a;
        a = *p0; a.x += v0.x; a.y += v0.y; *p0 = a;
        a = *p1; a.x += v1.x; a.y += v1.y; *p1 = a;
        a = *p2; a.x += v2.x; a.y += v2.y; *p2 = a;
        a = *p3; a.x += v3.x; a.y += v3.y; *p3 = a;
        if (lane == 0) { cnt[c0]++; cnt[c1]++; cnt[c2]++; cnt[c3]++; }
    }
    for (; row < n; row += stride) {
        float2 v = in2[(size_t)row * 64 + lane];
        int c = tgt[row];
        float2* p = (float2*)&tbl[c * DIM + lane * 2];
        float2 a = *p; a.x += v.x; a.y += v.y; *p = a;
        if (lane == 0) cnt[c]++;
    }
    __syncthreads();

    for (int i = tid; i < CD; i += 1024) {
        float s = 0.0f;
        #pragma unroll
        for (int ww = 0; ww < WPB; ww++) s += ls[ww * CD + i];
        unsafeAtomicAdd(&gsums[i], s);
    }
    if (tid < NCLS) {
        int s = 0;
        #pragma unroll
        for (int ww = 0; ww < WPB; ww++) s += lcnt[ww * NCLS + tid];
        atomicAdd(&gcounts[tid], s);
    }
}

// Pass 2: distances. R4: unroll 2 rows per 32-lane group (2 KB in flight per
// wave instead of 1 KB). Everything else unchanged from R3.
__global__ __launch_bounds__(256) void k_dist(const float4* __restrict__ in4,
                                              const int* __restrict__ tgt,
                                              const float* __restrict__ gsums,
                                              const int* __restrict__ gcounts,
                                              float* __restrict__ out,
                                              int n, float inv_n) {
    __shared__ __align__(16) float lcent[CD];
    __shared__ float red[256];
    const int tid = threadIdx.x;

    for (int i = tid; i < CD; i += 256)
        lcent[i] = gsums[i] / (float)gcounts[i >> 7];
    __syncthreads();

    const int l32 = tid & 31;
    const int rib = tid >> 5;              // 0..7
    const int stride = gridDim.x * 8;      // 8192
    float acc = 0.0f;
    int row = blockIdx.x * 8 + rib;

    for (; row + stride < n; row += 2 * stride) {
        float4 va = in4[(size_t)row * 32 + l32];
        float4 vb = in4[(size_t)(row + stride) * 32 + l32];
        int ca = tgt[row];
        int cb = tgt[row + stride];
        float4 ea = *(const float4*)&lcent[ca * DIM + l32 * 4];
        float4 eb = *(const float4*)&lcent[cb * DIM + l32 * 4];
        float dx = va.x - ea.x, dy = va.y - ea.y, dz = va.z - ea.z, dw = va.w - ea.w;
        float d2a = dx * dx + dy * dy + dz * dz + dw * dw;
        dx = vb.x - eb.x; dy = vb.y - eb.y; dz = vb.z - eb.z; dw = vb.w - eb.w;
        float d2b = dx * dx + dy * dy + dz * dz + dw * dw;
        for (int off = 16; off > 0; off >>= 1) {
            d2a += __shfl_down(d2a, off, 32);
            d2b += __shfl_down(d2b, off, 32);
        }
        if (l32 == 0) acc += sqrtf(d2a) + sqrtf(d2b);
    }
    for (; row < n; row += stride) {
        float4 v = in4[(size_t)row * 32 + l32];
        int c = tgt[row];
        float4 ce = *(const float4*)&lcent[c * DIM + l32 * 4];
        float dx = v.x - ce.x, dy = v.y - ce.y, dz = v.z - ce.z, dw = v.w - ce.w;
        float d2 = dx * dx + dy * dy + dz * dz + dw * dw;
        for (int off = 16; off > 0; off >>= 1)
            d2 += __shfl_down(d2, off, 32);
        if (l32 == 0) acc += sqrtf(d2);
    }

    red[tid] = acc;
    __syncthreads();
    for (int s = 128; s > 0; s >>= 1) {
        if (tid < s) red[tid] += red[tid + s];
        __syncthreads();
    }
    if (tid == 0) unsafeAtomicAdd(out, red[0] * inv_n);
}

extern "C" void kernel_launch(void* const* d_in, const int* in_sizes, int n_in,
                              void* d_out, int out_size, void* d_ws, size_t ws_size,
                              hipStream_t stream) {
    const float* in  = (const float*)d_in[0];
    const int*   tgt = (const int*)d_in[1];
    const int n = in_sizes[0] / DIM;

    float* gsums   = (float*)d_ws;             // [19][128]
    int*   gcounts = (int*)(gsums + CD);       // [19]
    float* out     = (float*)d_out;

    hipMemsetAsync(d_ws, 0, CD * sizeof(float) + NCLS * sizeof(int), stream);
    hipMemsetAsync(d_out, 0, sizeof(float), stream);

    k_accum<<<256, 1024, 0, stream>>>((const float2*)in, tgt, gsums, gcounts, n);
    k_dist<<<1024, 256, 0, stream>>>((const float4*)in, tgt, gsums, gcounts, out,
                                     n, 1.0f / (float)n);
}